// Round 1
// baseline (394.413 us; speedup 1.0000x reference)
//
#include <hip/hip_runtime.h>

using bf16x8 = __attribute__((ext_vector_type(8))) short;
using f32x4  = __attribute__((ext_vector_type(4))) float;

#define NB 64
#define CLN 1024
#define QLN 128
#define DDN 512

#define LDA 72    // 64 + 8 pad (ushorts) -> 144B row stride, 16B-aligned, 2-way-max bank alias
#define LDP 136   // 128 + 8 pad (ushorts) -> 272B row stride

__device__ __forceinline__ unsigned short f2bf(float x){
    union { float f; unsigned u; } v; v.f = x;
    unsigned r = v.u + 0x7FFFu + ((v.u >> 16) & 1u);   // RNE
    return (unsigned short)(r >> 16);
}

// K0: qT[b][d][j] = bf16(q[b][j][d]);  qbf[b][j][d] = bf16(q[b][j][d])
__global__ __launch_bounds__(256) void k0_transpose(const float* __restrict__ q,
        unsigned short* __restrict__ qT, unsigned short* __restrict__ qbf){
    __shared__ float tile[QLN][65];
    const int b  = blockIdx.x;
    const int d0 = blockIdx.y * 64;
    const int t  = threadIdx.x;
    {
        const int col = t & 63, rg = t >> 6;
        #pragma unroll 4
        for (int p = 0; p < 32; ++p){
            int j = p*4 + rg;
            float v = q[(size_t)(b*QLN + j)*DDN + d0 + col];
            tile[j][col] = v;
            qbf[(size_t)(b*QLN + j)*DDN + d0 + col] = f2bf(v);
        }
    }
    __syncthreads();
    {
        const int j = t & 127, dg = t >> 7;
        #pragma unroll 4
        for (int p = 0; p < 32; ++p){
            int dd = p*2 + dg;
            qT[(size_t)(b*DDN + d0 + dd)*QLN + j] = f2bf(tile[j][dd]);
        }
    }
}

// K0b: s_q[b][j] = dot(q[b][j][:], w_q)   (fp32, one wave per row)
__global__ __launch_bounds__(256) void k0b_sq(const float* __restrict__ q,
        const float* __restrict__ w_q, float* __restrict__ sq){
    const int b = blockIdx.x;
    const int t = threadIdx.x;
    const int wave = t >> 6, lane = t & 63;
    float wv[8];
    #pragma unroll
    for (int e=0;e<8;++e) wv[e] = w_q[lane*8+e];
    for (int j = wave; j < QLN; j += 4){
        const float* qr = q + (size_t)(b*QLN + j)*DDN + lane*8;
        float s = 0.f;
        #pragma unroll
        for (int e=0;e<8;++e) s += qr[e]*wv[e];
        #pragma unroll
        for (int m=1;m<64;m<<=1) s += __shfl_xor(s, m, 64);
        if (lane==0) sq[b*QLN + j] = s;
    }
}

// K1: per (b, 128-row i-tile): S = (c*w_cq) @ q^T (+s_q), row-softmax, m'->ws,
//     c2q = P @ q, write out quarters 0..2.
__global__ __launch_bounds__(256) void k1_main(
        const float* __restrict__ c, const unsigned short* __restrict__ qbf,
        const unsigned short* __restrict__ qT, const float* __restrict__ sq_ws,
        const float* __restrict__ w_cq, const float* __restrict__ w_c,
        float* __restrict__ out, float* __restrict__ mprime){
    __shared__ unsigned short smem[26624];   // 53248 B
    __shared__ float sm_sc[128];
    __shared__ float sm_sq[128];

    unsigned short* lds_a = smem;             // [128][LDA] during GEMM1
    unsigned short* lds_b = smem + 128*LDA;   // [128][LDA] during GEMM1
    unsigned short* sm_p  = smem;             // [128][LDP] after GEMM1 (aliases a+b)
    unsigned short* sm_qt = smem + 128*LDP;   // [128][LDA] during GEMM2

    const int b    = blockIdx.x >> 3;
    const int i0   = (blockIdx.x & 7) * 128;
    const int t    = threadIdx.x;
    const int lane = t & 63;
    const int wm   = t >> 6;      // wave id: rows [wm*32, wm*32+32)
    const int l15  = lane & 15;
    const int l4   = lane >> 4;

    f32x4 acc[2][8];
    #pragma unroll
    for (int mi=0;mi<2;++mi)
        #pragma unroll
        for (int ni=0;ni<8;++ni)
            acc[mi][ni] = f32x4{0.f,0.f,0.f,0.f};

    float sc_part[8];
    #pragma unroll
    for (int p=0;p<8;++p) sc_part[p]=0.f;

    const int arow = t >> 4;   // A staging: 16 rows/pass
    const int ac4  = t & 15;
    const int brow = t >> 3;   // B staging: 32 rows/pass
    const int bc8  = t & 7;

    // ---------------- GEMM1: S[i][j] = sum_d (c*w_cq)[i,d] * q[j,d] ----------------
    for (int kc = 0; kc < 8; ++kc){
        const int k0 = kc*64;
        float4 wcq = *(const float4*)(w_cq + k0 + ac4*4);
        float4 wc  = *(const float4*)(w_c  + k0 + ac4*4);
        #pragma unroll
        for (int p=0;p<8;++p){
            const int row = arow + p*16;
            float4 cv = *(const float4*)(c + (size_t)(b*CLN + i0 + row)*DDN + k0 + ac4*4);
            sc_part[p] += cv.x*wc.x + cv.y*wc.y + cv.z*wc.z + cv.w*wc.w;
            uint2 pk;
            pk.x = (unsigned)f2bf(cv.x*wcq.x) | ((unsigned)f2bf(cv.y*wcq.y) << 16);
            pk.y = (unsigned)f2bf(cv.z*wcq.z) | ((unsigned)f2bf(cv.w*wcq.w) << 16);
            *(uint2*)(lds_a + row*LDA + ac4*4) = pk;
        }
        #pragma unroll
        for (int p=0;p<4;++p){
            const int row = brow + p*32;
            *(bf16x8*)(lds_b + row*LDA + bc8*8) =
                *(const bf16x8*)(qbf + (size_t)(b*QLN + row)*DDN + k0 + bc8*8);
        }
        __syncthreads();
        #pragma unroll
        for (int ks=0; ks<2; ++ks){
            const int kk = ks*32 + l4*8;
            bf16x8 af[2], bfr[8];
            #pragma unroll
            for (int mi=0;mi<2;++mi)
                af[mi] = *(const bf16x8*)(lds_a + (wm*32 + mi*16 + l15)*LDA + kk);
            #pragma unroll
            for (int ni=0;ni<8;++ni)
                bfr[ni] = *(const bf16x8*)(lds_b + (ni*16 + l15)*LDA + kk);
            #pragma unroll
            for (int mi=0;mi<2;++mi)
                #pragma unroll
                for (int ni=0;ni<8;++ni)
                    acc[mi][ni] = __builtin_amdgcn_mfma_f32_16x16x32_bf16(af[mi], bfr[ni], acc[mi][ni], 0,0,0);
        }
        __syncthreads();
    }

    // s_c: reduce staging partials across the 16 lanes of each row group
    #pragma unroll
    for (int p=0;p<8;++p){
        float v = sc_part[p];
        #pragma unroll
        for (int m=1;m<16;m<<=1) v += __shfl_xor(v, m, 64);
        if (ac4 == 0) sm_sc[arow + p*16] = v;
    }
    if (t < 128) sm_sq[t] = sq_ws[b*QLN + t];
    __syncthreads();

    // ---------------- row softmax (each row fully within one wave) ----------------
    float sqv[8];
    #pragma unroll
    for (int ni=0;ni<8;++ni) sqv[ni] = sm_sq[ni*16 + l15];

    #pragma unroll
    for (int mi=0;mi<2;++mi){
        #pragma unroll
        for (int r=0;r<4;++r){
            float rmax = -1e30f;
            #pragma unroll
            for (int ni=0;ni<8;++ni){
                float v = acc[mi][ni][r] + sqv[ni];
                acc[mi][ni][r] = v;
                rmax = fmaxf(rmax, v);
            }
            #pragma unroll
            for (int m=1;m<16;m<<=1) rmax = fmaxf(rmax, __shfl_xor(rmax, m, 64));
            const int iloc = wm*32 + mi*16 + l4*4 + r;
            if (l15 == 0) mprime[b*CLN + i0 + iloc] = sm_sc[iloc] + rmax;
            float rsum = 0.f;
            #pragma unroll
            for (int ni=0;ni<8;++ni){
                float pv = __expf(acc[mi][ni][r] - rmax);
                acc[mi][ni][r] = pv;
                rsum += pv;
            }
            #pragma unroll
            for (int m=1;m<16;m<<=1) rsum += __shfl_xor(rsum, m, 64);
            const float inv = 1.f / rsum;
            #pragma unroll
            for (int ni=0;ni<8;++ni)
                sm_p[iloc*LDP + ni*16 + l15] = f2bf(acc[mi][ni][r] * inv);
        }
    }
    __syncthreads();

    // ---------------- GEMM2: c2q[i][d] = sum_j P[i][j] * q[j][d] ----------------
    const int qrow = t >> 3;   // 32 rows (local d) per pass
    const int qc8  = t & 7;

    for (int dc = 0; dc < 4; ++dc){
        f32x4 acc2[2][8];
        #pragma unroll
        for (int mi=0;mi<2;++mi)
            #pragma unroll
            for (int ni=0;ni<8;++ni)
                acc2[mi][ni] = f32x4{0.f,0.f,0.f,0.f};
        #pragma unroll
        for (int jh=0; jh<2; ++jh){
            __syncthreads();
            #pragma unroll
            for (int p=0;p<4;++p){
                const int row = qrow + p*32;   // local d row
                *(bf16x8*)(sm_qt + row*LDA + qc8*8) =
                    *(const bf16x8*)(qT + (size_t)(b*DDN + dc*128 + row)*QLN + jh*64 + qc8*8);
            }
            __syncthreads();
            #pragma unroll
            for (int ks=0; ks<2; ++ks){
                const int kkl = ks*32 + l4*8;
                const int kkp = jh*64 + kkl;
                bf16x8 af[2], bfr[8];
                #pragma unroll
                for (int mi=0;mi<2;++mi)
                    af[mi] = *(const bf16x8*)(sm_p + (wm*32 + mi*16 + l15)*LDP + kkp);
                #pragma unroll
                for (int ni=0;ni<8;++ni)
                    bfr[ni] = *(const bf16x8*)(sm_qt + (ni*16 + l15)*LDA + kkl);
                #pragma unroll
                for (int mi=0;mi<2;++mi)
                    #pragma unroll
                    for (int ni=0;ni<8;++ni)
                        acc2[mi][ni] = __builtin_amdgcn_mfma_f32_16x16x32_bf16(af[mi], bfr[ni], acc2[mi][ni], 0,0,0);
            }
        }
        // epilogue: quarters 0..2 for this d-chunk
        #pragma unroll
        for (int mi=0;mi<2;++mi){
            #pragma unroll
            for (int ni=0;ni<8;++ni){
                const int d = dc*128 + ni*16 + l15;
                #pragma unroll
                for (int r=0;r<4;++r){
                    const int iloc = wm*32 + mi*16 + l4*4 + r;
                    const size_t gi = (size_t)(b*CLN + i0 + iloc);
                    const float cv = c[gi*DDN + d];
                    const float v  = acc2[mi][ni][r];
                    float* orow = out + gi*(4*DDN);
                    orow[d]         = cv;
                    orow[DDN + d]   = v;
                    orow[2*DDN + d] = cv * v;
                }
            }
        }
    }
}

// K2: b_att = softmax_i(m'); q2c[b][d] = sum_i b_att[i]*c[b][i][d]
__global__ __launch_bounds__(256) void k2_q2c(
        const float* __restrict__ c, const float* __restrict__ mprime,
        float* __restrict__ q2c){
    __shared__ float sw[1024];
    __shared__ float red[8];
    __shared__ float part[128];
    const int b = blockIdx.x;
    const int d0 = blockIdx.y * 128;
    const int t = threadIdx.x, lane = t & 63, w = t >> 6;
    float mx = -1e30f;
    #pragma unroll
    for (int p=0;p<4;++p){
        float v = mprime[b*CLN + t + p*256];
        sw[t + p*256] = v;
        mx = fmaxf(mx, v);
    }
    #pragma unroll
    for (int m=1;m<64;m<<=1) mx = fmaxf(mx, __shfl_xor(mx, m, 64));
    if (lane==0) red[w] = mx;
    __syncthreads();
    mx = fmaxf(fmaxf(red[0],red[1]), fmaxf(red[2],red[3]));
    float sum = 0.f;
    #pragma unroll
    for (int p=0;p<4;++p){
        float e = __expf(sw[t + p*256] - mx);
        sw[t + p*256] = e;
        sum += e;
    }
    #pragma unroll
    for (int m=1;m<64;m<<=1) sum += __shfl_xor(sum, m, 64);
    if (lane==0) red[4+w] = sum;
    __syncthreads();
    const float inv = 1.f / (red[4]+red[5]+red[6]+red[7]);
    const int d = t & 127, g = t >> 7;   // split i-range across 2 groups
    const float* cp = c + (size_t)(b*CLN + g*512)*DDN + d0 + d;
    const float* swp = sw + g*512;
    float acc = 0.f;
    #pragma unroll 16
    for (int i=0;i<512;++i) acc += swp[i]*cp[(size_t)i*DDN];
    if (g==0) part[d] = acc;
    __syncthreads();
    if (g==1) q2c[b*DDN + d0 + d] = (part[d] + acc) * inv;
}

// K3: out quarter 3 = c * q2c (broadcast over i)
__global__ __launch_bounds__(256) void k3_cq2c(const float* __restrict__ c,
        const float* __restrict__ q2c, float* __restrict__ out){
    const int total = NB*CLN*DDN/4;   // float4 count
    for (int idx = blockIdx.x*256 + threadIdx.x; idx < total; idx += gridDim.x*256){
        const int d4  = idx & 127;
        const int rem = idx >> 7;
        const int i   = rem & 1023;
        const int b   = rem >> 10;
        float4 cv = *(const float4*)(c + (size_t)(((b<<10)+i)<<9) + (d4<<2));
        float4 qv = *(const float4*)(q2c + (b<<9) + (d4<<2));
        float4 o;
        o.x = cv.x*qv.x; o.y = cv.y*qv.y; o.z = cv.z*qv.z; o.w = cv.w*qv.w;
        *(float4*)(out + (size_t)(((b<<10)+i)<<11) + 3*DDN + (d4<<2)) = o;
    }
}

extern "C" void kernel_launch(void* const* d_in, const int* in_sizes, int n_in,
                              void* d_out, int out_size, void* d_ws, size_t ws_size,
                              hipStream_t stream) {
    const float* c    = (const float*)d_in[0];
    const float* q    = (const float*)d_in[1];
    const float* w_c  = (const float*)d_in[2];
    const float* w_q  = (const float*)d_in[4];
    const float* w_cq = (const float*)d_in[6];
    float* out = (float*)d_out;

    char* ws = (char*)d_ws;
    unsigned short* qT  = (unsigned short*)ws;                       // 8 MiB
    unsigned short* qbf = (unsigned short*)(ws + 8388608);           // 8 MiB
    float* sq  = (float*)(ws + 16777216);                            // 32 KiB
    float* mpr = (float*)(ws + 16777216 + 32768);                    // 256 KiB
    float* q2c = (float*)(ws + 16777216 + 32768 + 262144);           // 128 KiB

    k0_transpose<<<dim3(NB, 8), 256, 0, stream>>>(q, qT, qbf);
    k0b_sq<<<NB, 256, 0, stream>>>(q, w_q, sq);
    k1_main<<<NB*8, 256, 0, stream>>>(c, qbf, qT, sq, w_cq, w_c, out, mpr);
    k2_q2c<<<dim3(NB, 4), 256, 0, stream>>>(c, mpr, q2c);
    k3_cq2c<<<8192, 256, 0, stream>>>(c, q2c, out);
}

// Round 3
// 266.240 us; speedup vs baseline: 1.4814x; 1.4814x over previous
//
#include <hip/hip_runtime.h>

using bf16x8 = __attribute__((ext_vector_type(8))) short;
using f32x4  = __attribute__((ext_vector_type(4))) float;

#define NB 64
#define CLN 1024
#define QLN 128
#define DDN 512

typedef __attribute__((address_space(1))) const void GAS;
typedef __attribute__((address_space(3))) void LAS;

__device__ __forceinline__ unsigned short f2bf(float x){
    union { float f; unsigned u; } v; v.f = x;
    unsigned r = v.u + 0x7FFFu + ((v.u >> 16) & 1u);   // RNE
    return (unsigned short)(r >> 16);
}
__device__ __forceinline__ float bf2f(unsigned short u){
    union { unsigned u; float f; } v; v.u = ((unsigned)u) << 16; return v.f;
}

// ---------------- K0: qT[b][d][j] = bf16(q[b][j][d]); qbf[b][j][d] ----------------
__global__ __launch_bounds__(256) void k0_qprep(const float* __restrict__ q,
        unsigned short* __restrict__ qT, unsigned short* __restrict__ qbf){
    __shared__ float tile[QLN][65];
    const int b  = blockIdx.x;
    const int d0 = blockIdx.y * 64;
    const int t  = threadIdx.x;
    {
        const int col = t & 63, rg = t >> 6;
        #pragma unroll 4
        for (int p = 0; p < 32; ++p){
            int j = p*4 + rg;
            float v = q[(size_t)(b*QLN + j)*DDN + d0 + col];
            tile[j][col] = v;
            qbf[(size_t)(b*QLN + j)*DDN + d0 + col] = f2bf(v);
        }
    }
    __syncthreads();
    {
        const int j = t & 127, dg = t >> 7;
        #pragma unroll 4
        for (int p = 0; p < 32; ++p){
            int dd = p*2 + dg;
            qT[(size_t)(b*DDN + d0 + dd)*QLN + j] = f2bf(tile[j][dd]);
        }
    }
}

// ---------------- K0b: s_q[b][j] = q[b][j][:] . w_q ----------------
__global__ __launch_bounds__(256) void k0b_sq(const float* __restrict__ q,
        const float* __restrict__ w_q, float* __restrict__ sq){
    const int b = blockIdx.x;
    const int t = threadIdx.x;
    const int wave = t >> 6, lane = t & 63;
    float wv[8];
    #pragma unroll
    for (int e=0;e<8;++e) wv[e] = w_q[lane*8+e];
    for (int j = wave; j < QLN; j += 4){
        const float* qr = q + (size_t)(b*QLN + j)*DDN + lane*8;
        float s = 0.f;
        #pragma unroll
        for (int e=0;e<8;++e) s += qr[e]*wv[e];
        #pragma unroll
        for (int m=1;m<64;m<<=1) s += __shfl_xor(s, m, 64);
        if (lane==0) sq[b*QLN + j] = s;
    }
}

// ---------------- K0c: q0 = c (exact, nt); cbf = bf16(c*w_cq) into out-q3 slack;
//                       s_c = c . w_c; block 0 also writes inv_wcq ----------------
__global__ __launch_bounds__(256) void k0c_cprep(const float* __restrict__ c,
        const float* __restrict__ w_c, const float* __restrict__ w_cq,
        float* out, float* __restrict__ sc_ws, float* __restrict__ inv_ws){
    const int t = threadIdx.x, lane = t & 63, w = t >> 6;
    const int row0 = blockIdx.x*32 + w*8;
    float4 wc0 = *(const float4*)(w_c  + lane*8);
    float4 wc1 = *(const float4*)(w_c  + lane*8 + 4);
    float4 wq0 = *(const float4*)(w_cq + lane*8);
    float4 wq1 = *(const float4*)(w_cq + lane*8 + 4);
    #pragma unroll 2
    for (int p=0;p<8;++p){
        const size_t gi = (size_t)(row0 + p);
        const float* cr = c + gi*DDN + lane*8;
        f32x4 a  = *(const f32x4*)cr;
        f32x4 bb = *(const f32x4*)(cr+4);
        float s = a.x*wc0.x + a.y*wc0.y + a.z*wc0.z + a.w*wc0.w
                + bb.x*wc1.x + bb.y*wc1.y + bb.z*wc1.z + bb.w*wc1.w;
        #pragma unroll
        for (int m=1;m<64;m<<=1) s += __shfl_xor(s, m, 64);
        float* orow = out + gi*2048;
        __builtin_nontemporal_store(a,  (f32x4*)(orow + lane*8));
        __builtin_nontemporal_store(bb, (f32x4*)(orow + lane*8 + 4));
        uint4 pk;
        pk.x = (unsigned)f2bf(a.x*wq0.x)  | ((unsigned)f2bf(a.y*wq0.y)  << 16);
        pk.y = (unsigned)f2bf(a.z*wq0.z)  | ((unsigned)f2bf(a.w*wq0.w)  << 16);
        pk.z = (unsigned)f2bf(bb.x*wq1.x) | ((unsigned)f2bf(bb.y*wq1.y) << 16);
        pk.w = (unsigned)f2bf(bb.z*wq1.z) | ((unsigned)f2bf(bb.w*wq1.w) << 16);
        *(uint4*)((unsigned short*)(orow + 1792) + lane*8) = pk;   // cbf, normal store (cacheable)
        if (lane==0) sc_ws[gi] = s;
    }
    if (blockIdx.x == 0){
        for (int d=t; d<DDN; d+=256){
            float wv = w_cq[d];
            inv_ws[d] = (fabsf(wv) > 1e-35f) ? 1.0f/wv : 0.0f;
        }
    }
}

// staging: one wave fills 4 chunks of 8 rows (128B/row, XOR-swizzled source)
__device__ __forceinline__ void stage_tile(const float* out, size_t girow0, int kc,
        unsigned short* buf, int wm, int lane){
    const int rsub = lane >> 3, c16 = lane & 7;
    #pragma unroll
    for (int r=0;r<4;++r){
        const int chunk = wm*4 + r;
        const int row   = chunk*8 + rsub;
        const int col16 = c16 ^ (row & 7);
        const unsigned short* g =
            (const unsigned short*)(out + (girow0 + row)*2048 + 1792) + kc*64 + col16*8;
        __builtin_amdgcn_global_load_lds((GAS*)g, (LAS*)(buf + chunk*512), 16, 0, 0);
    }
}

// ---------------- K1: GEMM1 (S=cbf@qbf^T) -> softmax -> GEMM2 (P@q via qT) ->
//                  q1,q2 nt-stores + per-tile {M_t,S_t,v_t} for b_att ----------------
__global__ __launch_bounds__(256,3) void k1_main(
        float* out, const unsigned short* __restrict__ qbf,
        const unsigned short* __restrict__ qT, const float* __restrict__ sq_ws,
        const float* __restrict__ sc_ws, const float* __restrict__ inv_ws,
        float* __restrict__ vts, float* __restrict__ Mts, float* __restrict__ Sts){
    __shared__ unsigned short sm_u[16384];     // 32KB: 2 A-bufs (8192 each) / P alias
    __shared__ float sm_vw[4][512];            // 8KB per-wave v_t slabs
    __shared__ float sm_sc[128], sm_sq[128], sm_m[128], sm_red[8];

    const int bid  = blockIdx.x;
    const int swzb = (bid & 7)*64 + (bid >> 3);    // XCD-aware swizzle (512 = 8*64)
    const int b    = swzb >> 3;
    const int tile = swzb & 7;
    const int i0   = tile * 128;
    const int t    = threadIdx.x;
    const int lane = t & 63;
    const int wm   = t >> 6;
    const int l15  = lane & 15;
    const int l4   = lane >> 4;
    const size_t girow0 = (size_t)(b*CLN + i0);

    if (t < 128){ sm_sc[t] = sc_ws[girow0 + t]; sm_sq[t] = sq_ws[b*QLN + t]; }

    f32x4 acc[2][8];
    #pragma unroll
    for (int mi=0;mi<2;++mi)
        #pragma unroll
        for (int ni=0;ni<8;++ni) acc[mi][ni] = f32x4{0.f,0.f,0.f,0.f};

    // ---- GEMM1 ----
    stage_tile(out, girow0, 0, sm_u, wm, lane);
    __syncthreads();
    const unsigned short* qbbase = qbf + (size_t)b*QLN*DDN;
    for (int kc=0; kc<8; ++kc){
        const int cur = kc & 1;
        if (kc < 7) stage_tile(out, girow0, kc+1, sm_u + (cur^1)*8192, wm, lane);
        const char* abase = (const char*)sm_u + cur*16384;
        #pragma unroll
        for (int ks=0; ks<2; ++ks){
            const int kk2 = (ks*32 + l4*8)*2;
            bf16x8 af[2], bfr[8];
            #pragma unroll
            for (int mi=0;mi<2;++mi){
                const int row = wm*32 + mi*16 + l15;
                af[mi] = *(const bf16x8*)(abase + row*128 + (kk2 ^ ((row&7)<<4)));
            }
            #pragma unroll
            for (int ni=0;ni<8;++ni)
                bfr[ni] = *(const bf16x8*)(qbbase + (size_t)(ni*16+l15)*DDN + kc*64 + ks*32 + l4*8);
            #pragma unroll
            for (int mi=0;mi<2;++mi)
                #pragma unroll
                for (int ni=0;ni<8;++ni)
                    acc[mi][ni] = __builtin_amdgcn_mfma_f32_16x16x32_bf16(af[mi], bfr[ni], acc[mi][ni], 0,0,0);
        }
        __syncthreads();
    }

    // ---- row softmax (row entirely within a 16-lane group), P -> sm_u swizzled ----
    float sqv[8];
    #pragma unroll
    for (int ni=0;ni<8;++ni) sqv[ni] = sm_sq[ni*16 + l15];
    #pragma unroll
    for (int mi=0;mi<2;++mi){
        #pragma unroll
        for (int r=0;r<4;++r){
            float rmax = -1e30f;
            #pragma unroll
            for (int ni=0;ni<8;++ni){
                float v = acc[mi][ni][r] + sqv[ni];
                acc[mi][ni][r] = v;
                rmax = fmaxf(rmax, v);
            }
            #pragma unroll
            for (int m=1;m<16;m<<=1) rmax = fmaxf(rmax, __shfl_xor(rmax, m, 64));
            const int iloc = wm*32 + mi*16 + l4*4 + r;
            if (l15 == 0) sm_m[iloc] = sm_sc[iloc] + rmax;
            float rsum = 0.f;
            #pragma unroll
            for (int ni=0;ni<8;++ni){
                float pv = __expf(acc[mi][ni][r] - rmax);
                acc[mi][ni][r] = pv;
                rsum += pv;
            }
            #pragma unroll
            for (int m=1;m<16;m<<=1) rsum += __shfl_xor(rsum, m, 64);
            const float inv = 1.f / rsum;
            #pragma unroll
            for (int ni=0;ni<8;++ni){
                const int colb = (ni*16 + l15)*2;
                *(unsigned short*)((char*)sm_u + iloc*256 + (colb ^ ((iloc&7)<<4)))
                    = f2bf(acc[mi][ni][r] * inv);
            }
        }
    }
    __syncthreads();   // P + sm_m visible

    // ---- tile max/sum for b_att ----
    float e0 = -1e30f;
    if (t < 128) e0 = sm_m[t];
    float v0 = e0;
    #pragma unroll
    for (int m=1;m<64;m<<=1) v0 = fmaxf(v0, __shfl_xor(v0, m, 64));
    if (lane==0) sm_red[wm] = v0;
    __syncthreads();
    const float mt = fmaxf(sm_red[0], sm_red[1]);
    float es = (t < 128) ? __expf(sm_m[t] - mt) : 0.f;
    #pragma unroll
    for (int m=1;m<64;m<<=1) es += __shfl_xor(es, m, 64);
    if (lane==0) sm_red[4+wm] = es;
    __syncthreads();
    const float St = sm_red[4]+sm_red[5]+sm_red[6]+sm_red[7];

    float wrow[2][4];
    #pragma unroll
    for (int mi=0;mi<2;++mi)
        #pragma unroll
        for (int r=0;r<4;++r)
            wrow[mi][r] = __expf(sm_m[wm*32 + mi*16 + l4*4 + r] - mt);
    #pragma unroll
    for (int k=0;k<8;++k) sm_vw[wm][lane + k*64] = 0.f;   // own wave's slab only

    // ---- GEMM2 + epilogue ----
    const unsigned short* qtbase = qT + (size_t)b*DDN*QLN;
    for (int dc=0; dc<4; ++dc){
        f32x4 acc2[2][8];
        #pragma unroll
        for (int mi=0;mi<2;++mi)
            #pragma unroll
            for (int ni=0;ni<8;++ni) acc2[mi][ni] = f32x4{0.f,0.f,0.f,0.f};
        #pragma unroll
        for (int jh=0; jh<2; ++jh){
            #pragma unroll
            for (int ks=0; ks<2; ++ks){
                const int kkp2 = (jh*64 + ks*32 + l4*8)*2;
                bf16x8 af[2], bfr[8];
                #pragma unroll
                for (int mi=0;mi<2;++mi){
                    const int row = wm*32 + mi*16 + l15;
                    af[mi] = *(const bf16x8*)((const char*)sm_u + row*256 + (kkp2 ^ ((row&7)<<4)));
                }
                #pragma unroll
                for (int ni=0;ni<8;++ni)
                    bfr[ni] = *(const bf16x8*)(qtbase + (size_t)(dc*128 + ni*16 + l15)*QLN + jh*64 + ks*32 + l4*8);
                #pragma unroll
                for (int mi=0;mi<2;++mi)
                    #pragma unroll
                    for (int ni=0;ni<8;++ni)
                        acc2[mi][ni] = __builtin_amdgcn_mfma_f32_16x16x32_bf16(af[mi], bfr[ni], acc2[mi][ni], 0,0,0);
            }
        }
        float invw[8];
        #pragma unroll
        for (int ni=0;ni<8;++ni) invw[ni] = inv_ws[dc*128 + ni*16 + l15];
        float vpart[8];
        #pragma unroll
        for (int ni=0;ni<8;++ni) vpart[ni] = 0.f;
        #pragma unroll
        for (int mi=0;mi<2;++mi){
            #pragma unroll
            for (int r=0;r<4;++r){
                const int rl = wm*32 + mi*16 + l4*4 + r;
                const unsigned short* cb =
                    (const unsigned short*)(out + (girow0 + rl)*2048 + 1792) + dc*128;
                float* orow = out + (girow0 + rl)*2048;
                const float wgt = wrow[mi][r];
                #pragma unroll
                for (int ni=0;ni<8;++ni){
                    const int dl = ni*16 + l15;
                    const float cv = bf2f(cb[dl]) * invw[ni];
                    const float v  = acc2[mi][ni][r];
                    __builtin_nontemporal_store(v,    orow + 512  + dc*128 + dl);
                    __builtin_nontemporal_store(cv*v, orow + 1024 + dc*128 + dl);
                    vpart[ni] += wgt * cv;
                }
            }
        }
        #pragma unroll
        for (int ni=0;ni<8;++ni){
            float v = vpart[ni];
            v += __shfl_xor(v, 16, 64);
            v += __shfl_xor(v, 32, 64);
            if (l4 == 0) sm_vw[wm][dc*128 + ni*16 + l15] = v;
        }
    }
    __syncthreads();
    for (int d=t; d<DDN; d+=256){
        float v = sm_vw[0][d] + sm_vw[1][d] + sm_vw[2][d] + sm_vw[3][d];
        vts[(size_t)(b*8 + tile)*DDN + d] = v;
    }
    if (t == 0){ Mts[b*8 + tile] = mt; Sts[b*8 + tile] = St; }
}

// ---------------- K2: combine 8 tiles -> q2c[b][d] ----------------
__global__ __launch_bounds__(256) void k2_combine(const float* __restrict__ vts,
        const float* __restrict__ Mts, const float* __restrict__ Sts,
        float* __restrict__ q2c){
    const int b = blockIdx.x, t = threadIdx.x;
    float Mt[8]; float M = -1e30f;
    #pragma unroll
    for (int i=0;i<8;++i){ Mt[i] = Mts[b*8+i]; M = fmaxf(M, Mt[i]); }
    float coef[8]; float denom = 0.f;
    #pragma unroll
    for (int i=0;i<8;++i){ coef[i] = __expf(Mt[i]-M); denom += coef[i]*Sts[b*8+i]; }
    const float inv = 1.f/denom;
    for (int d=t; d<DDN; d+=256){
        float s = 0.f;
        #pragma unroll
        for (int i=0;i<8;++i) s += coef[i]*vts[(size_t)(b*8+i)*DDN + d];
        q2c[b*DDN + d] = s*inv;
    }
}

// ---------------- K3: q3 = c * q2c (c reconstructed from cbf in q3 slack) ----------------
__global__ __launch_bounds__(256) void k3_cq2c(float* out,
        const float* __restrict__ q2c, const float* __restrict__ inv_ws){
    const int t = threadIdx.x;
    const int rloc = t >> 6, ch = t & 63;
    for (int pass=0; pass<8; ++pass){
        const size_t rb = (size_t)blockIdx.x + (size_t)pass*2048;
        const size_t gi = rb*4 + rloc;
        const int b = (int)(gi >> 10);
        const unsigned short* cb = (const unsigned short*)(out + gi*2048 + 1792) + ch*8;
        uint4 raw = *(const uint4*)cb;
        const float* qp = q2c + b*DDN + ch*8;
        float4 qa = *(const float4*)qp;
        float4 qb = *(const float4*)(qp+4);
        const float* ip = inv_ws + ch*8;
        float4 ia = *(const float4*)ip;
        float4 ib = *(const float4*)(ip+4);
        f32x4 o0, o1;
        o0.x = bf2f((unsigned short)(raw.x & 0xffff)) * ia.x * qa.x;
        o0.y = bf2f((unsigned short)(raw.x >> 16))    * ia.y * qa.y;
        o0.z = bf2f((unsigned short)(raw.y & 0xffff)) * ia.z * qa.z;
        o0.w = bf2f((unsigned short)(raw.y >> 16))    * ia.w * qa.w;
        o1.x = bf2f((unsigned short)(raw.z & 0xffff)) * ib.x * qb.x;
        o1.y = bf2f((unsigned short)(raw.z >> 16))    * ib.y * qb.y;
        o1.z = bf2f((unsigned short)(raw.w & 0xffff)) * ib.z * qb.z;
        o1.w = bf2f((unsigned short)(raw.w >> 16))    * ib.w * qb.w;
        __syncthreads();   // all 4 rows' cbf read before any q3 overwrite
        f32x4* wp = (f32x4*)(out + gi*2048 + 1536) + ch*2;
        __builtin_nontemporal_store(o0, wp);
        __builtin_nontemporal_store(o1, wp+1);
    }
}

extern "C" void kernel_launch(void* const* d_in, const int* in_sizes, int n_in,
                              void* d_out, int out_size, void* d_ws, size_t ws_size,
                              hipStream_t stream) {
    const float* c    = (const float*)d_in[0];
    const float* q    = (const float*)d_in[1];
    const float* w_c  = (const float*)d_in[2];
    const float* w_q  = (const float*)d_in[4];
    const float* w_cq = (const float*)d_in[6];
    float* out = (float*)d_out;

    char* ws = (char*)d_ws;
    unsigned short* qT  = (unsigned short*)ws;                         // 8 MiB
    unsigned short* qbf = (unsigned short*)(ws + 8388608);             // 8 MiB
    float* sq  = (float*)(ws + 16777216);                              // 32 KB
    float* sc  = (float*)(ws + 16777216 + 32768);                      // 256 KB
    float* inv = (float*)(ws + 16777216 + 32768 + 262144);             // 2 KB
    float* Mts = (float*)(ws + 16777216 + 32768 + 262144 + 2048);      // 2 KB
    float* Sts = (float*)(ws + 16777216 + 32768 + 262144 + 4096);      // 2 KB
    float* vts = (float*)(ws + 16777216 + 32768 + 262144 + 6144);      // 1 MiB
    float* q2c = (float*)(ws + 16777216 + 32768 + 262144 + 6144 + 1048576); // 128 KB

    k0_qprep<<<dim3(NB, 8), 256, 0, stream>>>(q, qT, qbf);
    k0b_sq<<<NB, 256, 0, stream>>>(q, w_q, sq);
    k0c_cprep<<<2048, 256, 0, stream>>>(c, w_c, w_cq, out, sc, inv);
    k1_main<<<NB*8, 256, 0, stream>>>(out, qbf, qT, sq, sc, inv, vts, Mts, Sts);
    k2_combine<<<NB, 256, 0, stream>>>(vts, Mts, Sts, q2c);
    k3_cq2c<<<2048, 256, 0, stream>>>(out, q2c, inv);
}